// Round 21
// baseline (283.860 us; speedup 1.0000x reference)
//
#include <hip/hip_runtime.h>

typedef unsigned short ushort_t;
typedef short bf16x8 __attribute__((ext_vector_type(8)));
typedef float f32x4 __attribute__((ext_vector_type(4)));
typedef unsigned int u32x4 __attribute__((ext_vector_type(4)));
typedef _Float16 half2t __attribute__((ext_vector_type(2)));

#define LOG2E 1.4426950408889634f
#define LN2   0.6931471805599453f

__device__ __forceinline__ float bf2f(ushort_t u) {
    union { unsigned int i; float f; } v; v.i = ((unsigned int)u) << 16; return v.f;
}
__device__ __forceinline__ ushort_t f2bf(float f) {
    union { float f; unsigned int i; } v; v.f = f;
    unsigned int u = v.i;
    unsigned int r = (u + 0x7FFFu + ((u >> 16) & 1u)) >> 16;
    return (ushort_t)r;
}
__device__ __forceinline__ float hsum4(f32x4 v) { return (v[0] + v[1]) + (v[2] + v[3]); }
__device__ __forceinline__ float frcp(float x) { return __builtin_amdgcn_rcpf(x); }
__device__ __forceinline__ float fsig(float x) { return frcp(1.f + __expf(-x)); }
__device__ __forceinline__ float ftanh(float x) { return 1.f - 2.f * frcp(1.f + __expf(2.f * x)); }
__device__ __forceinline__ int hpad(int e) { return e + ((e >> 4) << 2); }
__device__ __forceinline__ float dot2(unsigned int w, unsigned int h, float acc) {
    union { unsigned int u; half2t h2; } a, b;
    a.u = w; b.u = h;
    return __builtin_amdgcn_fdot2(a.h2, b.h2, acc, false);
}
__device__ __forceinline__ float dpp_xor1_add(float x) {
    int m = __builtin_amdgcn_update_dpp(0, __builtin_bit_cast(int, x), 0xB1, 0xF, 0xF, true);
    return x + __builtin_bit_cast(float, m);
}
__device__ __forceinline__ float dpp_xor2_add(float x) {
    int m = __builtin_amdgcn_update_dpp(0, __builtin_bit_cast(int, x), 0x4E, 0xF, 0xF, true);
    return x + __builtin_bit_cast(float, m);
}
__device__ __forceinline__ ushort_t f2h(float f) {
    union { _Float16 h; ushort_t s; } c; c.h = (_Float16)f; return c.s;
}

// ---------------- weight prep: enc_Wih/enc_Whh/dec_Whh/doc_Whh -> f16 (parallel, first) ----------------
__global__ void k_prep(const float* __restrict__ encWih, const float* __restrict__ encWhh,
                       const float* __restrict__ decWhh, const float* __restrict__ docWhh,
                       ushort_t* __restrict__ wencih, ushort_t* __restrict__ wenchh,
                       ushort_t* __restrict__ wdechh, ushort_t* __restrict__ wdoc) {
    int i = blockIdx.x * blockDim.x + threadIdx.x;  // u64 units (4 f16 each)
    const float* src; ushort_t* dst; int off;
    if (i < 6144)       { src = encWih; dst = wencih; off = i; }
    else if (i < 18432) { src = encWhh; dst = wenchh; off = i - 6144; }
    else if (i < 30720) { src = decWhh; dst = wdechh; off = i - 18432; }
    else if (i < 43008) { src = docWhh; dst = wdoc;   off = i - 30720; }
    else return;
    f32x4 v = ((const f32x4*)src)[off];
    union { ushort_t u[4]; unsigned long long q; } p;
    p.u[0] = f2h(v[0]); p.u[1] = f2h(v[1]); p.u[2] = f2h(v[2]); p.u[3] = f2h(v[3]);
    ((unsigned long long*)dst)[off] = p.q;
}

// ---------------- encoder GRU: f16 weights + dot2; h state fp32 in owner regs ----------------
__global__ __launch_bounds__(768, 1) void k_encoder(
    const int* __restrict__ doc, const float* __restrict__ emb,
    const ushort_t* __restrict__ wih16, const ushort_t* __restrict__ whh16,
    const float* __restrict__ bih, const float* __restrict__ bhh,
    float* __restrict__ sent) {
    int s = blockIdx.x, t = threadIdx.x;
    int half = t & 1, j = t >> 1;
    __shared__ unsigned int xpk[32], hpk_[64];  // x,h packed f16 pairs
    __shared__ float gi[384], gh[384];
    __shared__ int toks[48];
    u32x4 wi[4], wh[8];
    const ushort_t* pih = wih16 + j * 64 + half * 32;
    const ushort_t* phh = whh16 + j * 128 + half * 64;
#pragma unroll
    for (int k = 0; k < 4; k++) wi[k] = *(const u32x4*)(pih + k * 8);
#pragma unroll
    for (int k = 0; k < 8; k++) wh[k] = *(const u32x4*)(phh + k * 8);
    float bi = bih[j], bh = bhh[j];
    if (t < 48) toks[t] = doc[s * 48 + t];
    if (t < 64) hpk_[t] = 0u;
    __syncthreads();
    if (t < 64) ((ushort_t*)xpk)[t] = f2h(emb[(size_t)toks[0] * 64 + t]);
    float h_own = 0.f;
    __syncthreads();
    const unsigned int* xb = xpk + half * 16;
    const unsigned int* hb = hpk_ + half * 32;
    for (int tt = 0; tt < 48; tt++) {
        float xnext = (t < 64 && tt + 1 < 48) ? emb[(size_t)toks[tt + 1] * 64 + t] : 0.f;
        float a0 = 0.f, a1 = 0.f, b0 = 0.f, b1 = 0.f;
#pragma unroll
        for (int k = 0; k < 4; k++) {
            u32x4 xv = *(const u32x4*)(xb + k * 4);
            a0 = dot2(wi[k][0], xv[0], a0); a1 = dot2(wi[k][1], xv[1], a1);
            a0 = dot2(wi[k][2], xv[2], a0); a1 = dot2(wi[k][3], xv[3], a1);
        }
#pragma unroll
        for (int k = 0; k < 8; k++) {
            u32x4 hv = *(const u32x4*)(hb + k * 4);
            b0 = dot2(wh[k][0], hv[0], b0); b1 = dot2(wh[k][1], hv[1], b1);
            b0 = dot2(wh[k][2], hv[2], b0); b1 = dot2(wh[k][3], hv[3], b1);
        }
        float a = dpp_xor1_add(a0 + a1), b = dpp_xor1_add(b0 + b1);
        if (half == 0) { gi[j] = a + bi; gh[j] = b + bh; }
        __syncthreads();
        if (t < 128) {
            float r = fsig(gi[t] + gh[t]);
            float z = fsig(gi[t + 128] + gh[t + 128]);
            float n = ftanh(gi[t + 256] + r * gh[t + 256]);
            h_own = (1.f - z) * n + z * h_own;
            ((ushort_t*)hpk_)[t] = f2h(h_own);
        }
        if (t < 64 && tt + 1 < 48) ((ushort_t*)xpk)[t] = f2h(xnext);
        __syncthreads();
    }
    if (t < 128) sent[s * 128 + t] = h_own;
}

// ---------------- doc-GRU input gates (parallel over steps) ----------------
__global__ void k_doc_gi(const float* __restrict__ sv, const float* __restrict__ Wih,
                         const float* __restrict__ bih, float* __restrict__ gidoc) {
    int i = blockIdx.x, j = threadIdx.x;
    __shared__ f32x4 v4[32];
    if (j < 128) ((float*)v4)[j] = sv[i * 128 + j];
    __syncthreads();
    f32x4 a0 = {0,0,0,0}, a1 = {0,0,0,0};
#pragma unroll
    for (int k = 0; k < 32; k += 2) {
        a0 += *(const f32x4*)(Wih + j * 128 + k * 4) * v4[k];
        a1 += *(const f32x4*)(Wih + j * 128 + (k + 1) * 4) * v4[k + 1];
    }
    gidoc[i * 384 + j] = bih[j] + hsum4(a0 + a1);
}

// ---------------- FUSED mid kernel, 512 thr (r19-verified) ----------------
__global__ __launch_bounds__(512, 1) __attribute__((amdgpu_waves_per_eu(1, 2)))
void k_mid(
    const float* __restrict__ gidoc, const ushort_t* __restrict__ wdoc,
    const float* __restrict__ dbhh, float* __restrict__ dvec,
    const int* __restrict__ doc, const float* __restrict__ demb,
    const float* __restrict__ dWih, float* __restrict__ gidec,
    const float* __restrict__ fcW, ushort_t* __restrict__ fcWb,
    const float* __restrict__ fcb, float* __restrict__ fcbs) {
    int bid = blockIdx.x, t = threadIdx.x;

    if (bid == 0) {
        // ---- doc GRU ----
        int q = t & 3, e = t >> 2;
        __shared__ unsigned int hpk[2][64];
        u32x4 wr4[4], wz4[4], wn4[4];
        const ushort_t* wbase = wdoc + e * 128 + q * 32;
#pragma unroll
        for (int k = 0; k < 4; k++) {
            wr4[k] = *(const u32x4*)(wbase + k * 8);
            wz4[k] = *(const u32x4*)(wbase + 128 * 128 + k * 8);
            wn4[k] = *(const u32x4*)(wbase + 256 * 128 + k * 8);
        }
        float biasr = dbhh[e], biasz = dbhh[128 + e], biasn = dbhh[256 + e];
        float cr = gidoc[e], cz = gidoc[128 + e], cn = gidoc[256 + e];
        if (t < 64) hpk[0][t] = 0u;
        float he = 0.f;
        __syncthreads();
        for (int i = 0; i < 128; i++) {
            float nr = 0.f, nz = 0.f, nn = 0.f;
            if (i + 1 < 128) {
                const float* g = gidoc + (i + 1) * 384;
                nr = g[e]; nz = g[128 + e]; nn = g[256 + e];
            }
            const unsigned int* hp = &hpk[i & 1][q * 16];
            u32x4 hv[4];
            hv[0] = *(const u32x4*)(hp);
            hv[1] = *(const u32x4*)(hp + 4);
            hv[2] = *(const u32x4*)(hp + 8);
            hv[3] = *(const u32x4*)(hp + 12);
            float ra0 = 0.f, ra1 = 0.f, za0 = 0.f, za1 = 0.f, na0 = 0.f, na1 = 0.f;
#pragma unroll
            for (int k = 0; k < 4; k++) {
                u32x4 h4 = hv[k];
                ra0 = dot2(wr4[k][0], h4[0], ra0); ra1 = dot2(wr4[k][1], h4[1], ra1);
                ra0 = dot2(wr4[k][2], h4[2], ra0); ra1 = dot2(wr4[k][3], h4[3], ra1);
                za0 = dot2(wz4[k][0], h4[0], za0); za1 = dot2(wz4[k][1], h4[1], za1);
                za0 = dot2(wz4[k][2], h4[2], za0); za1 = dot2(wz4[k][3], h4[3], za1);
                na0 = dot2(wn4[k][0], h4[0], na0); na1 = dot2(wn4[k][1], h4[1], na1);
                na0 = dot2(wn4[k][2], h4[2], na0); na1 = dot2(wn4[k][3], h4[3], na1);
            }
            float rp = ra0 + ra1, zp = za0 + za1, np = na0 + na1;
            rp = dpp_xor2_add(dpp_xor1_add(rp));
            zp = dpp_xor2_add(dpp_xor1_add(zp));
            np = dpp_xor2_add(dpp_xor1_add(np));
            float r = fsig(cr + rp + biasr);
            float z = fsig(cz + zp + biasz);
            float n = ftanh(cn + r * (np + biasn));
            he = (1.f - z) * n + z * he;
            if (q == 0) ((ushort_t*)&hpk[(i & 1) ^ 1][0])[e] = f2h(he);
            __syncthreads();
            cr = nr; cz = nz; cn = nn;
        }
        if (q == 0) dvec[e] = he;
        return;
    }

    if (bid <= 128) {
        // ---- decoder input gates, x-part only ----
        int s = bid - 1;
        __shared__ float xs[80];
        __shared__ int toks[48];
        if (t < 47) toks[t] = doc[s * 48 + t];
        __syncthreads();
        if (t < 64) xs[hpad(t)] = demb[(size_t)toks[0] * 64 + t];
        __syncthreads();
        f32x4 wih[16];
        if (t < 384) {
#pragma unroll
            for (int k = 0; k < 16; k++) wih[k] = *(const f32x4*)(dWih + t * 192 + k * 4);
        }
        for (int tt = 0; tt < 47; tt++) {
            float xnext = (t < 64 && tt + 1 < 47) ? demb[(size_t)toks[tt + 1] * 64 + t] : 0.f;
            if (t < 384) {
                f32x4 a0 = {0,0,0,0}, a1 = {0,0,0,0};
#pragma unroll
                for (int k = 0; k < 16; k += 2) {
                    a0 += wih[k] * (*(const f32x4*)(xs + k * 4 + (k >> 2) * 4));
                    a1 += wih[k + 1] * (*(const f32x4*)(xs + (k + 1) * 4 + ((k + 1) >> 2) * 4));
                }
                gidec[(tt * 128 + s) * 384 + t] = hsum4(a0 + a1);
            }
            __syncthreads();
            if (t < 64 && tt + 1 < 47) xs[hpad(t)] = xnext;
            __syncthreads();
        }
        return;
    }

    // ---- fc_W -> bf16 * log2e; fc_b -> * log2e ----
    int i = (bid - 129) * 512 + t;
    if (i < 1024000) {
        f32x4 v = ((const f32x4*)fcW)[i];
        union { ushort_t u[4]; unsigned long long qq; } p;
        p.u[0] = f2bf(v[0] * LOG2E); p.u[1] = f2bf(v[1] * LOG2E);
        p.u[2] = f2bf(v[2] * LOG2E); p.u[3] = f2bf(v[3] * LOG2E);
        ((unsigned long long*)fcWb)[i] = p.qq;
    } else if (i < 1024000 + 8000) {
        int k = i - 1024000;
        f32x4 b = ((const f32x4*)fcb)[k];
        ((f32x4*)fcbs)[k] = b * LOG2E;
    }
}

// ---------------- decoder GRU: ctx GEMV fused in prologue; f16 whh + dot2; h2 -> bf16 ----------------
__global__ __launch_bounds__(768, 1) void k_dec_seq(
    const float* __restrict__ gidec, const ushort_t* __restrict__ whh16,
    const float* __restrict__ bhh, const float* __restrict__ sent,
    const float* __restrict__ dWih, const float* __restrict__ dbih,
    const float* __restrict__ dvec, ushort_t* __restrict__ h2b) {
    int s = blockIdx.x, t = threadIdx.x, half = t & 1, j = t >> 1;
    __shared__ unsigned int hpk_[64];
    __shared__ float gi[384], gh[384];
    __shared__ float gctxs[384];
    __shared__ f32x4 dv4[32];
    u32x4 wh[8];
    const ushort_t* phh = whh16 + j * 128 + half * 64;
#pragma unroll
    for (int k = 0; k < 8; k++) wh[k] = *(const u32x4*)(phh + k * 8);
    float bh = bhh[j];
    if (t < 128) ((float*)dv4)[t] = dvec[t];
    __syncthreads();
    // per-block redundant ctx gate: gctxs[row] = dbih[row] + dWih[row,64:192] @ dvec
    if (t < 384) {
        f32x4 c0 = {0,0,0,0}, c1 = {0,0,0,0};
#pragma unroll
        for (int k = 0; k < 32; k += 2) {
            c0 += *(const f32x4*)(dWih + t * 192 + 64 + k * 4) * dv4[k];
            c1 += *(const f32x4*)(dWih + t * 192 + 64 + (k + 1) * 4) * dv4[k + 1];
        }
        gctxs[t] = dbih[t] + hsum4(c0 + c1);
    }
    float h_own = 0.f;
    if (t < 128) { h_own = sent[s * 128 + t]; ((ushort_t*)hpk_)[t] = f2h(h_own); }
    __syncthreads();
    float g_me = gctxs[j];
    float gval = (half == 0) ? (gidec[s * 384 + j] + g_me) : 0.f;
    const unsigned int* hb = hpk_ + half * 32;
    for (int i = 0; i < 47; i++) {
        float gnext = (half == 0 && i + 1 < 47) ? (gidec[((i + 1) * 128 + s) * 384 + j] + g_me) : 0.f;
        float b0 = 0.f, b1 = 0.f;
#pragma unroll
        for (int k = 0; k < 8; k++) {
            u32x4 hv = *(const u32x4*)(hb + k * 4);
            b0 = dot2(wh[k][0], hv[0], b0); b1 = dot2(wh[k][1], hv[1], b1);
            b0 = dot2(wh[k][2], hv[2], b0); b1 = dot2(wh[k][3], hv[3], b1);
        }
        float b = dpp_xor1_add(b0 + b1);
        if (half == 0) { gh[j] = b + bh; gi[j] = gval; }
        __syncthreads();
        if (t < 128) {
            float r = fsig(gi[t] + gh[t]);
            float z = fsig(gi[t + 128] + gh[t + 128]);
            float n = ftanh(gi[t + 256] + r * gh[t + 256]);
            h_own = (1.f - z) * n + z * h_own;
            ((ushort_t*)hpk_)[t] = f2h(h_own);
            h2b[(i * 128 + s) * 128 + t] = f2bf(h_own);
        }
        __syncthreads();
        gval = gnext;
    }
}

// ---------------- target logits ----------------
__global__ void k_tl(const int* __restrict__ doc, const ushort_t* __restrict__ h2b,
                     const ushort_t* __restrict__ wb, const float* __restrict__ fcb,
                     float* __restrict__ tl) {
    int r = blockIdx.x * 4 + (threadIdx.x >> 6);
    int lane = threadIdx.x & 63;
    int s = r & 127, t = r >> 7;
    int tok = doc[s * 48 + t + 1];
    const ushort_t* hp = h2b + r * 128;
    const ushort_t* wp = wb + tok * 128;
    float acc = bf2f(hp[lane]) * bf2f(wp[lane]) + bf2f(hp[lane + 64]) * bf2f(wp[lane + 64]);
#pragma unroll
    for (int m = 32; m >= 1; m >>= 1) acc += __shfl_xor(acc, m);
    if (lane == 0) tl[r] = acc * LN2 + fcb[tok];
}

// ---------------- fused logits GEMM + sum(exp2): 32KB dbuf, 8 waves/SIMD (4 blocks/CU) ----------------
// r20 lever: kernel needs only 40 VGPR -> fits the 64-VGPR/8-wave budget. 940 blocks all
// co-resident (one round); 32 waves/CU hide the per-tile barrier drain across blocks.
#define LSE_VC 20
#define LSE_NC 1600
#define LSE_NT 25
__global__ __launch_bounds__(512, 8) void k_lse(
    const ushort_t* __restrict__ h2b, const ushort_t* __restrict__ wb,
    const float* __restrict__ fcbs, float* __restrict__ parts) {
    int rb = blockIdx.x / LSE_VC;
    int vc = blockIdx.x % LSE_VC;
    int t = threadIdx.x;
    int wave = t >> 6, lane = t & 63;
    int rg = wave >> 1, cg = wave & 1;
    int q = lane >> 4, l15 = lane & 15;

    __shared__ __align__(16) char ldsB[32768];  // 2 x 16KB B tile

    int row0 = rb * 128 + rg * 32;
    bf16x8 a[2][4];
    const ushort_t* ap = h2b + (size_t)(row0 + l15) * 128 + q * 8;
#pragma unroll
    for (int m = 0; m < 2; m++)
#pragma unroll
        for (int c = 0; c < 4; c++) a[m][c] = *(const bf16x8*)(ap + m * 2048 + c * 32);

    const char* wbB = (const char*)wb;
    int so = ((t >> 4) << 8) + (((t & 15) ^ ((t >> 4) & 15)) << 4);
    char* dst1 = ldsB + wave * 1024;

#define LSE_STAGE(buf, cb) do { \
    const char* g_ = wbB + (size_t)(cb) * 256 + so; \
    char* d_ = dst1 + (buf) * 16384; \
    __builtin_amdgcn_global_load_lds((const __attribute__((address_space(1))) unsigned int*)(g_), \
                                     (__attribute__((address_space(3))) unsigned int*)(d_), 16, 0, 0); \
    __builtin_amdgcn_global_load_lds((const __attribute__((address_space(1))) unsigned int*)(g_ + 8192), \
                                     (__attribute__((address_space(3))) unsigned int*)(d_ + 8192), 16, 0, 0); \
} while (0)

    int ra[2][4];
#pragma unroll
    for (int c2 = 0; c2 < 2; c2++)
#pragma unroll
        for (int c = 0; c < 4; c++)
            ra[c2][c] = (cg * 32 + c2 * 16 + l15) * 256 + (((q + 4 * c) ^ l15) << 4);

    int cb0 = vc * LSE_NC;
    f32x4 se[2] = {{0,0,0,0},{0,0,0,0}};

    LSE_STAGE(0, cb0);
    __syncthreads();
    int cur = 0;
    for (int tile = 0; tile < LSE_NT; ++tile) {
        if (tile + 1 < LSE_NT) LSE_STAGE(cur ^ 1, cb0 + (tile + 1) * 64);
        const char* bb = ldsB + (cur << 14);
        int colg = cb0 + tile * 64 + cg * 32 + l15;
        float bs0 = fcbs[colg], bs1 = fcbs[colg + 16];
        f32x4 acc[2][2] = {{{0,0,0,0},{0,0,0,0}},{{0,0,0,0},{0,0,0,0}}};
#pragma unroll
        for (int c = 0; c < 4; c++) {
            bf16x8 b0 = *(const bf16x8*)(bb + ra[0][c]);
            bf16x8 b1 = *(const bf16x8*)(bb + ra[1][c]);
            acc[0][0] = __builtin_amdgcn_mfma_f32_16x16x32_bf16(a[0][c], b0, acc[0][0], 0, 0, 0);
            acc[1][0] = __builtin_amdgcn_mfma_f32_16x16x32_bf16(a[1][c], b0, acc[1][0], 0, 0, 0);
            acc[0][1] = __builtin_amdgcn_mfma_f32_16x16x32_bf16(a[0][c], b1, acc[0][1], 0, 0, 0);
            acc[1][1] = __builtin_amdgcn_mfma_f32_16x16x32_bf16(a[1][c], b1, acc[1][1], 0, 0, 0);
        }
#pragma unroll
        for (int m = 0; m < 2; m++) {
#pragma unroll
            for (int r = 0; r < 4; r++)
                se[m][r] += __builtin_amdgcn_exp2f(acc[m][0][r] + bs0)
                          + __builtin_amdgcn_exp2f(acc[m][1][r] + bs1);
        }
        __syncthreads();
        cur ^= 1;
    }

#pragma unroll
    for (int m = 0; m < 2; m++) {
        f32x4 v = se[m];
#pragma unroll
        for (int d = 1; d < 16; d <<= 1) {
            v[0] += __shfl_xor(v[0], d);
            v[1] += __shfl_xor(v[1], d);
            v[2] += __shfl_xor(v[2], d);
            v[3] += __shfl_xor(v[3], d);
        }
        if (l15 == 0) {
            float* p = parts + (size_t)(vc * 2 + cg) * 6016 + row0 + m * 16 + q * 4;
            p[0] = v[0]; p[1] = v[1]; p[2] = v[2]; p[3] = v[3];
        }
    }
}

// ---------------- per-row loss ----------------
__global__ void k_final1(const float* __restrict__ parts, const float* __restrict__ tl,
                         float* __restrict__ rowloss) {
    int r = blockIdx.x * 128 + threadIdx.x;
    float tot = 0.f;
#pragma unroll 8
    for (int c = 0; c < 40; c++) tot += parts[(size_t)c * 6016 + r];
    rowloss[r] = logf(tot) - tl[r];
}

// ---------------- final mean ----------------
__global__ void k_final2(const float* __restrict__ rowloss, float* __restrict__ out) {
    __shared__ float red[512];
    int tid = threadIdx.x;
    float acc = 0.f;
    for (int r = tid; r < 6016; r += 512) acc += rowloss[r];
    red[tid] = acc;
    __syncthreads();
    for (int s = 256; s > 0; s >>= 1) {
        if (tid < s) red[tid] += red[tid + s];
        __syncthreads();
    }
    if (tid == 0) out[0] = red[0] / 6016.f;
}

extern "C" void kernel_launch(void* const* d_in, const int* in_sizes, int n_in,
                              void* d_out, int out_size, void* d_ws, size_t ws_size,
                              hipStream_t stream) {
    const int* doc = (const int*)d_in[0];
    const float* enc_emb = (const float*)d_in[1];
    const float* enc_Wih = (const float*)d_in[2];
    const float* enc_Whh = (const float*)d_in[3];
    const float* enc_bih = (const float*)d_in[4];
    const float* enc_bhh = (const float*)d_in[5];
    const float* doc_Wih = (const float*)d_in[6];
    const float* doc_Whh = (const float*)d_in[7];
    const float* doc_bih = (const float*)d_in[8];
    const float* doc_bhh = (const float*)d_in[9];
    const float* dec_emb = (const float*)d_in[10];
    const float* dec_Wih = (const float*)d_in[11];
    const float* dec_Whh = (const float*)d_in[12];
    const float* dec_bih = (const float*)d_in[13];
    const float* dec_bhh = (const float*)d_in[14];
    const float* fc_W = (const float*)d_in[15];
    const float* fc_b = (const float*)d_in[16];

    char* ws = (char*)d_ws;
    ushort_t* fcWb   = (ushort_t*)(ws + 0);          // 8,192,000 B
    float* sent      = (float*)(ws + 8192000);       // 65,536 B
    float* dvec      = (float*)(ws + 8257536);       // 512 B
    float* gidoc     = (float*)(ws + 8258048);       // 196,608 B
    float* gidec     = (float*)(ws + 8456192);       // 9,240,576 B
    ushort_t* h2b    = (ushort_t*)(ws + 17696768);   // 1,540,096 B
    float* tl        = (float*)(ws + 19236864);      // 24,064 B
    float* parts     = (float*)(ws + 19260928);      // 40*6016*4 = 962,560 B
    float* rowloss   = (float*)(ws + 20223488);      // 24,064 B
    ushort_t* wdoc   = (ushort_t*)(ws + 20247552);   // 98,304 B
    float* fcbs      = (float*)(ws + 20345856);      // 128,000 B
    ushort_t* wencih = (ushort_t*)(ws + 20473856);   // 49,152 B
    ushort_t* wenchh = (ushort_t*)(ws + 20523008);   // 98,304 B
    ushort_t* wdechh = (ushort_t*)(ws + 20621312);   // 98,304 B
    float* out = (float*)d_out;

    k_prep<<<168, 256, 0, stream>>>(enc_Wih, enc_Whh, dec_Whh, doc_Whh,
                                    wencih, wenchh, wdechh, wdoc);
    k_encoder<<<128, 768, 0, stream>>>(doc, enc_emb, wencih, wenchh, enc_bih, enc_bhh, sent);
    k_doc_gi<<<128, 384, 0, stream>>>(sent, doc_Wih, doc_bih, gidoc);
    k_mid<<<1 + 128 + 2016, 512, 0, stream>>>(gidoc, wdoc, doc_bhh, dvec,
                                              doc, dec_emb, dec_Wih, gidec,
                                              fc_W, fcWb, fc_b, fcbs);
    k_dec_seq<<<128, 768, 0, stream>>>(gidec, wdechh, dec_bhh, sent,
                                       dec_Wih, dec_bih, dvec, h2b);
    k_tl<<<1504, 256, 0, stream>>>(doc, h2b, fcWb, fc_b, tl);
    k_lse<<<47 * LSE_VC, 512, 0, stream>>>(h2b, fcWb, fcbs, parts);
    k_final1<<<47, 128, 0, stream>>>(parts, tl, rowloss);
    k_final2<<<1, 512, 0, stream>>>(rowloss, out);
}

// Round 22
// 229.568 us; speedup vs baseline: 1.2365x; 1.2365x over previous
//
#include <hip/hip_runtime.h>

typedef unsigned short ushort_t;
typedef short bf16x8 __attribute__((ext_vector_type(8)));
typedef float f32x4 __attribute__((ext_vector_type(4)));
typedef unsigned int u32x4 __attribute__((ext_vector_type(4)));
typedef _Float16 half2t __attribute__((ext_vector_type(2)));

#define LOG2E 1.4426950408889634f
#define LN2   0.6931471805599453f

__device__ __forceinline__ float bf2f(ushort_t u) {
    union { unsigned int i; float f; } v; v.i = ((unsigned int)u) << 16; return v.f;
}
__device__ __forceinline__ ushort_t f2bf(float f) {
    union { float f; unsigned int i; } v; v.f = f;
    unsigned int u = v.i;
    unsigned int r = (u + 0x7FFFu + ((u >> 16) & 1u)) >> 16;
    return (ushort_t)r;
}
__device__ __forceinline__ float hsum4(f32x4 v) { return (v[0] + v[1]) + (v[2] + v[3]); }
__device__ __forceinline__ float frcp(float x) { return __builtin_amdgcn_rcpf(x); }
__device__ __forceinline__ float fsig(float x) { return frcp(1.f + __expf(-x)); }
__device__ __forceinline__ float ftanh(float x) { return 1.f - 2.f * frcp(1.f + __expf(2.f * x)); }
__device__ __forceinline__ int hpad(int e) { return e + ((e >> 4) << 2); }
__device__ __forceinline__ float dot2(unsigned int w, unsigned int h, float acc) {
    union { unsigned int u; half2t h2; } a, b;
    a.u = w; b.u = h;
    return __builtin_amdgcn_fdot2(a.h2, b.h2, acc, false);
}
__device__ __forceinline__ float dpp_xor1_add(float x) {
    int m = __builtin_amdgcn_update_dpp(0, __builtin_bit_cast(int, x), 0xB1, 0xF, 0xF, true);
    return x + __builtin_bit_cast(float, m);
}
__device__ __forceinline__ float dpp_xor2_add(float x) {
    int m = __builtin_amdgcn_update_dpp(0, __builtin_bit_cast(int, x), 0x4E, 0xF, 0xF, true);
    return x + __builtin_bit_cast(float, m);
}
__device__ __forceinline__ ushort_t f2h(float f) {
    union { _Float16 h; ushort_t s; } c; c.h = (_Float16)f; return c.s;
}

// ---------------- weight prep: enc_Wih/enc_Whh/dec_Whh/doc_Whh -> f16 (parallel, first) ----------------
__global__ void k_prep(const float* __restrict__ encWih, const float* __restrict__ encWhh,
                       const float* __restrict__ decWhh, const float* __restrict__ docWhh,
                       ushort_t* __restrict__ wencih, ushort_t* __restrict__ wenchh,
                       ushort_t* __restrict__ wdechh, ushort_t* __restrict__ wdoc) {
    int i = blockIdx.x * blockDim.x + threadIdx.x;  // u64 units (4 f16 each)
    const float* src; ushort_t* dst; int off;
    if (i < 6144)       { src = encWih; dst = wencih; off = i; }
    else if (i < 18432) { src = encWhh; dst = wenchh; off = i - 6144; }
    else if (i < 30720) { src = decWhh; dst = wdechh; off = i - 18432; }
    else if (i < 43008) { src = docWhh; dst = wdoc;   off = i - 30720; }
    else return;
    f32x4 v = ((const f32x4*)src)[off];
    union { ushort_t u[4]; unsigned long long q; } p;
    p.u[0] = f2h(v[0]); p.u[1] = f2h(v[1]); p.u[2] = f2h(v[2]); p.u[3] = f2h(v[3]);
    ((unsigned long long*)dst)[off] = p.q;
}

// ---------------- encoder GRU: f16 weights + dot2; h state fp32 in owner regs ----------------
__global__ __launch_bounds__(768, 1) void k_encoder(
    const int* __restrict__ doc, const float* __restrict__ emb,
    const ushort_t* __restrict__ wih16, const ushort_t* __restrict__ whh16,
    const float* __restrict__ bih, const float* __restrict__ bhh,
    float* __restrict__ sent) {
    int s = blockIdx.x, t = threadIdx.x;
    int half = t & 1, j = t >> 1;
    __shared__ unsigned int xpk[32], hpk_[64];  // x,h packed f16 pairs
    __shared__ float gi[384], gh[384];
    __shared__ int toks[48];
    u32x4 wi[4], wh[8];
    const ushort_t* pih = wih16 + j * 64 + half * 32;
    const ushort_t* phh = whh16 + j * 128 + half * 64;
#pragma unroll
    for (int k = 0; k < 4; k++) wi[k] = *(const u32x4*)(pih + k * 8);
#pragma unroll
    for (int k = 0; k < 8; k++) wh[k] = *(const u32x4*)(phh + k * 8);
    float bi = bih[j], bh = bhh[j];
    if (t < 48) toks[t] = doc[s * 48 + t];
    if (t < 64) hpk_[t] = 0u;
    __syncthreads();
    if (t < 64) ((ushort_t*)xpk)[t] = f2h(emb[(size_t)toks[0] * 64 + t]);
    float h_own = 0.f;
    __syncthreads();
    const unsigned int* xb = xpk + half * 16;
    const unsigned int* hb = hpk_ + half * 32;
    for (int tt = 0; tt < 48; tt++) {
        float xnext = (t < 64 && tt + 1 < 48) ? emb[(size_t)toks[tt + 1] * 64 + t] : 0.f;
        float a0 = 0.f, a1 = 0.f, b0 = 0.f, b1 = 0.f;
#pragma unroll
        for (int k = 0; k < 4; k++) {
            u32x4 xv = *(const u32x4*)(xb + k * 4);
            a0 = dot2(wi[k][0], xv[0], a0); a1 = dot2(wi[k][1], xv[1], a1);
            a0 = dot2(wi[k][2], xv[2], a0); a1 = dot2(wi[k][3], xv[3], a1);
        }
#pragma unroll
        for (int k = 0; k < 8; k++) {
            u32x4 hv = *(const u32x4*)(hb + k * 4);
            b0 = dot2(wh[k][0], hv[0], b0); b1 = dot2(wh[k][1], hv[1], b1);
            b0 = dot2(wh[k][2], hv[2], b0); b1 = dot2(wh[k][3], hv[3], b1);
        }
        float a = dpp_xor1_add(a0 + a1), b = dpp_xor1_add(b0 + b1);
        if (half == 0) { gi[j] = a + bi; gh[j] = b + bh; }
        __syncthreads();
        if (t < 128) {
            float r = fsig(gi[t] + gh[t]);
            float z = fsig(gi[t + 128] + gh[t + 128]);
            float n = ftanh(gi[t + 256] + r * gh[t + 256]);
            h_own = (1.f - z) * n + z * h_own;
            ((ushort_t*)hpk_)[t] = f2h(h_own);
        }
        if (t < 64 && tt + 1 < 48) ((ushort_t*)xpk)[t] = f2h(xnext);
        __syncthreads();
    }
    if (t < 128) sent[s * 128 + t] = h_own;
}

// ---------------- doc-GRU input gates (parallel over steps) ----------------
__global__ void k_doc_gi(const float* __restrict__ sv, const float* __restrict__ Wih,
                         const float* __restrict__ bih, float* __restrict__ gidoc) {
    int i = blockIdx.x, j = threadIdx.x;
    __shared__ f32x4 v4[32];
    if (j < 128) ((float*)v4)[j] = sv[i * 128 + j];
    __syncthreads();
    f32x4 a0 = {0,0,0,0}, a1 = {0,0,0,0};
#pragma unroll
    for (int k = 0; k < 32; k += 2) {
        a0 += *(const f32x4*)(Wih + j * 128 + k * 4) * v4[k];
        a1 += *(const f32x4*)(Wih + j * 128 + (k + 1) * 4) * v4[k + 1];
    }
    gidoc[i * 384 + j] = bih[j] + hsum4(a0 + a1);
}

// ---------------- FUSED mid kernel, 512 thr (r19-verified) ----------------
__global__ __launch_bounds__(512, 1) __attribute__((amdgpu_waves_per_eu(1, 2)))
void k_mid(
    const float* __restrict__ gidoc, const ushort_t* __restrict__ wdoc,
    const float* __restrict__ dbhh, float* __restrict__ dvec,
    const int* __restrict__ doc, const float* __restrict__ demb,
    const float* __restrict__ dWih, float* __restrict__ gidec,
    const float* __restrict__ fcW, ushort_t* __restrict__ fcWb,
    const float* __restrict__ fcb, float* __restrict__ fcbs) {
    int bid = blockIdx.x, t = threadIdx.x;

    if (bid == 0) {
        // ---- doc GRU ----
        int q = t & 3, e = t >> 2;
        __shared__ unsigned int hpk[2][64];
        u32x4 wr4[4], wz4[4], wn4[4];
        const ushort_t* wbase = wdoc + e * 128 + q * 32;
#pragma unroll
        for (int k = 0; k < 4; k++) {
            wr4[k] = *(const u32x4*)(wbase + k * 8);
            wz4[k] = *(const u32x4*)(wbase + 128 * 128 + k * 8);
            wn4[k] = *(const u32x4*)(wbase + 256 * 128 + k * 8);
        }
        float biasr = dbhh[e], biasz = dbhh[128 + e], biasn = dbhh[256 + e];
        float cr = gidoc[e], cz = gidoc[128 + e], cn = gidoc[256 + e];
        if (t < 64) hpk[0][t] = 0u;
        float he = 0.f;
        __syncthreads();
        for (int i = 0; i < 128; i++) {
            float nr = 0.f, nz = 0.f, nn = 0.f;
            if (i + 1 < 128) {
                const float* g = gidoc + (i + 1) * 384;
                nr = g[e]; nz = g[128 + e]; nn = g[256 + e];
            }
            const unsigned int* hp = &hpk[i & 1][q * 16];
            u32x4 hv[4];
            hv[0] = *(const u32x4*)(hp);
            hv[1] = *(const u32x4*)(hp + 4);
            hv[2] = *(const u32x4*)(hp + 8);
            hv[3] = *(const u32x4*)(hp + 12);
            float ra0 = 0.f, ra1 = 0.f, za0 = 0.f, za1 = 0.f, na0 = 0.f, na1 = 0.f;
#pragma unroll
            for (int k = 0; k < 4; k++) {
                u32x4 h4 = hv[k];
                ra0 = dot2(wr4[k][0], h4[0], ra0); ra1 = dot2(wr4[k][1], h4[1], ra1);
                ra0 = dot2(wr4[k][2], h4[2], ra0); ra1 = dot2(wr4[k][3], h4[3], ra1);
                za0 = dot2(wz4[k][0], h4[0], za0); za1 = dot2(wz4[k][1], h4[1], za1);
                za0 = dot2(wz4[k][2], h4[2], za0); za1 = dot2(wz4[k][3], h4[3], za1);
                na0 = dot2(wn4[k][0], h4[0], na0); na1 = dot2(wn4[k][1], h4[1], na1);
                na0 = dot2(wn4[k][2], h4[2], na0); na1 = dot2(wn4[k][3], h4[3], na1);
            }
            float rp = ra0 + ra1, zp = za0 + za1, np = na0 + na1;
            rp = dpp_xor2_add(dpp_xor1_add(rp));
            zp = dpp_xor2_add(dpp_xor1_add(zp));
            np = dpp_xor2_add(dpp_xor1_add(np));
            float r = fsig(cr + rp + biasr);
            float z = fsig(cz + zp + biasz);
            float n = ftanh(cn + r * (np + biasn));
            he = (1.f - z) * n + z * he;
            if (q == 0) ((ushort_t*)&hpk[(i & 1) ^ 1][0])[e] = f2h(he);
            __syncthreads();
            cr = nr; cz = nz; cn = nn;
        }
        if (q == 0) dvec[e] = he;
        return;
    }

    if (bid <= 128) {
        // ---- decoder input gates, x-part only ----
        int s = bid - 1;
        __shared__ float xs[80];
        __shared__ int toks[48];
        if (t < 47) toks[t] = doc[s * 48 + t];
        __syncthreads();
        if (t < 64) xs[hpad(t)] = demb[(size_t)toks[0] * 64 + t];
        __syncthreads();
        f32x4 wih[16];
        if (t < 384) {
#pragma unroll
            for (int k = 0; k < 16; k++) wih[k] = *(const f32x4*)(dWih + t * 192 + k * 4);
        }
        for (int tt = 0; tt < 47; tt++) {
            float xnext = (t < 64 && tt + 1 < 47) ? demb[(size_t)toks[tt + 1] * 64 + t] : 0.f;
            if (t < 384) {
                f32x4 a0 = {0,0,0,0}, a1 = {0,0,0,0};
#pragma unroll
                for (int k = 0; k < 16; k += 2) {
                    a0 += wih[k] * (*(const f32x4*)(xs + k * 4 + (k >> 2) * 4));
                    a1 += wih[k + 1] * (*(const f32x4*)(xs + (k + 1) * 4 + ((k + 1) >> 2) * 4));
                }
                gidec[(tt * 128 + s) * 384 + t] = hsum4(a0 + a1);
            }
            __syncthreads();
            if (t < 64 && tt + 1 < 47) xs[hpad(t)] = xnext;
            __syncthreads();
        }
        return;
    }

    // ---- fc_W -> bf16 * log2e; fc_b -> * log2e ----
    int i = (bid - 129) * 512 + t;
    if (i < 1024000) {
        f32x4 v = ((const f32x4*)fcW)[i];
        union { ushort_t u[4]; unsigned long long qq; } p;
        p.u[0] = f2bf(v[0] * LOG2E); p.u[1] = f2bf(v[1] * LOG2E);
        p.u[2] = f2bf(v[2] * LOG2E); p.u[3] = f2bf(v[3] * LOG2E);
        ((unsigned long long*)fcWb)[i] = p.qq;
    } else if (i < 1024000 + 8000) {
        int k = i - 1024000;
        f32x4 b = ((const f32x4*)fcb)[k];
        ((f32x4*)fcbs)[k] = b * LOG2E;
    }
}

// ---------------- decoder GRU: ctx GEMV fused in prologue; f16 whh + dot2; h2 -> bf16 ----------------
__global__ __launch_bounds__(768, 1) void k_dec_seq(
    const float* __restrict__ gidec, const ushort_t* __restrict__ whh16,
    const float* __restrict__ bhh, const float* __restrict__ sent,
    const float* __restrict__ dWih, const float* __restrict__ dbih,
    const float* __restrict__ dvec, ushort_t* __restrict__ h2b) {
    int s = blockIdx.x, t = threadIdx.x, half = t & 1, j = t >> 1;
    __shared__ unsigned int hpk_[64];
    __shared__ float gi[384], gh[384];
    __shared__ float gctxs[384];
    __shared__ f32x4 dv4[32];
    u32x4 wh[8];
    const ushort_t* phh = whh16 + j * 128 + half * 64;
#pragma unroll
    for (int k = 0; k < 8; k++) wh[k] = *(const u32x4*)(phh + k * 8);
    float bh = bhh[j];
    if (t < 128) ((float*)dv4)[t] = dvec[t];
    __syncthreads();
    // per-block redundant ctx gate: gctxs[row] = dbih[row] + dWih[row,64:192] @ dvec
    if (t < 384) {
        f32x4 c0 = {0,0,0,0}, c1 = {0,0,0,0};
#pragma unroll
        for (int k = 0; k < 32; k += 2) {
            c0 += *(const f32x4*)(dWih + t * 192 + 64 + k * 4) * dv4[k];
            c1 += *(const f32x4*)(dWih + t * 192 + 64 + (k + 1) * 4) * dv4[k + 1];
        }
        gctxs[t] = dbih[t] + hsum4(c0 + c1);
    }
    float h_own = 0.f;
    if (t < 128) { h_own = sent[s * 128 + t]; ((ushort_t*)hpk_)[t] = f2h(h_own); }
    __syncthreads();
    float g_me = gctxs[j];
    float gval = (half == 0) ? (gidec[s * 384 + j] + g_me) : 0.f;
    const unsigned int* hb = hpk_ + half * 32;
    for (int i = 0; i < 47; i++) {
        float gnext = (half == 0 && i + 1 < 47) ? (gidec[((i + 1) * 128 + s) * 384 + j] + g_me) : 0.f;
        float b0 = 0.f, b1 = 0.f;
#pragma unroll
        for (int k = 0; k < 8; k++) {
            u32x4 hv = *(const u32x4*)(hb + k * 4);
            b0 = dot2(wh[k][0], hv[0], b0); b1 = dot2(wh[k][1], hv[1], b1);
            b0 = dot2(wh[k][2], hv[2], b0); b1 = dot2(wh[k][3], hv[3], b1);
        }
        float b = dpp_xor1_add(b0 + b1);
        if (half == 0) { gh[j] = b + bh; gi[j] = gval; }
        __syncthreads();
        if (t < 128) {
            float r = fsig(gi[t] + gh[t]);
            float z = fsig(gi[t + 128] + gh[t + 128]);
            float n = ftanh(gi[t + 256] + r * gh[t + 256]);
            h_own = (1.f - z) * n + z * h_own;
            ((ushort_t*)hpk_)[t] = f2h(h_own);
            h2b[(i * 128 + s) * 128 + t] = f2bf(h_own);
        }
        __syncthreads();
        gval = gnext;
    }
}

// ---------------- target logits ----------------
__global__ void k_tl(const int* __restrict__ doc, const ushort_t* __restrict__ h2b,
                     const ushort_t* __restrict__ wb, const float* __restrict__ fcb,
                     float* __restrict__ tl) {
    int r = blockIdx.x * 4 + (threadIdx.x >> 6);
    int lane = threadIdx.x & 63;
    int s = r & 127, t = r >> 7;
    int tok = doc[s * 48 + t + 1];
    const ushort_t* hp = h2b + r * 128;
    const ushort_t* wp = wb + tok * 128;
    float acc = bf2f(hp[lane]) * bf2f(wp[lane]) + bf2f(hp[lane + 64]) * bf2f(wp[lane + 64]);
#pragma unroll
    for (int m = 32; m >= 1; m >>= 1) acc += __shfl_xor(acc, m);
    if (lane == 0) tl[r] = acc * LN2 + fcb[tok];
}

// ---------------- fused logits GEMM + sum(exp2): 2-tile pairs per barrier, 1-round grid ----------------
// r21 lesson: launch_bounds(512,8) capped VGPR at 32 -> spill (WRITE 50MB, 124us).
// This is the r18/r20-verified config: (512,2), 4x16KB LDS, pair staging, VGPR~40-48.
#define LSE_VC 10
#define LSE_NC 3200
#define LSE_NPAIR 25
__global__ __launch_bounds__(512, 2) void k_lse(
    const ushort_t* __restrict__ h2b, const ushort_t* __restrict__ wb,
    const float* __restrict__ fcbs, float* __restrict__ parts) {
    int rb = blockIdx.x / LSE_VC;
    int vc = blockIdx.x % LSE_VC;
    int t = threadIdx.x;
    int wave = t >> 6, lane = t & 63;
    int rg = wave >> 1, cg = wave & 1;
    int q = lane >> 4, l15 = lane & 15;

    __shared__ __align__(16) char ldsB[65536];  // 4 x 16KB B tile

    int row0 = rb * 128 + rg * 32;
    bf16x8 a[2][4];
    const ushort_t* ap = h2b + (size_t)(row0 + l15) * 128 + q * 8;
#pragma unroll
    for (int m = 0; m < 2; m++)
#pragma unroll
        for (int c = 0; c < 4; c++) a[m][c] = *(const bf16x8*)(ap + m * 2048 + c * 32);

    const char* wbB = (const char*)wb;
    int so = ((t >> 4) << 8) + (((t & 15) ^ ((t >> 4) & 15)) << 4);
    char* dst1 = ldsB + wave * 1024;

#define LSE_STAGE(buf, cb) do { \
    const char* g_ = wbB + (size_t)(cb) * 256 + so; \
    char* d_ = dst1 + (buf) * 16384; \
    __builtin_amdgcn_global_load_lds((const __attribute__((address_space(1))) unsigned int*)(g_), \
                                     (__attribute__((address_space(3))) unsigned int*)(d_), 16, 0, 0); \
    __builtin_amdgcn_global_load_lds((const __attribute__((address_space(1))) unsigned int*)(g_ + 8192), \
                                     (__attribute__((address_space(3))) unsigned int*)(d_ + 8192), 16, 0, 0); \
} while (0)

    int ra[2][4];
#pragma unroll
    for (int c2 = 0; c2 < 2; c2++)
#pragma unroll
        for (int c = 0; c < 4; c++)
            ra[c2][c] = (cg * 32 + c2 * 16 + l15) * 256 + (((q + 4 * c) ^ l15) << 4);

    int cb0 = vc * LSE_NC;
    f32x4 se[2] = {{0,0,0,0},{0,0,0,0}};

    LSE_STAGE(0, cb0);
    LSE_STAGE(1, cb0 + 64);
    __syncthreads();
    int cur = 0;
    for (int it = 0; it < LSE_NPAIR; ++it) {
        if (it + 1 < LSE_NPAIR) {
            LSE_STAGE(2 * (cur ^ 1),     cb0 + (2 * it + 2) * 64);
            LSE_STAGE(2 * (cur ^ 1) + 1, cb0 + (2 * it + 3) * 64);
        }
        int colg = cb0 + 2 * it * 64 + cg * 32 + l15;
        float bA0 = fcbs[colg],      bA1 = fcbs[colg + 16];
        float bB0 = fcbs[colg + 64], bB1 = fcbs[colg + 80];
#pragma unroll
        for (int half = 0; half < 2; half++) {
            const char* bb = ldsB + (size_t)(2 * cur + half) * 16384;
            float bs0 = half ? bB0 : bA0;
            float bs1 = half ? bB1 : bA1;
            f32x4 acc[2][2] = {{{0,0,0,0},{0,0,0,0}},{{0,0,0,0},{0,0,0,0}}};
#pragma unroll
            for (int c = 0; c < 4; c++) {
                bf16x8 b0 = *(const bf16x8*)(bb + ra[0][c]);
                bf16x8 b1 = *(const bf16x8*)(bb + ra[1][c]);
                acc[0][0] = __builtin_amdgcn_mfma_f32_16x16x32_bf16(a[0][c], b0, acc[0][0], 0, 0, 0);
                acc[1][0] = __builtin_amdgcn_mfma_f32_16x16x32_bf16(a[1][c], b0, acc[1][0], 0, 0, 0);
                acc[0][1] = __builtin_amdgcn_mfma_f32_16x16x32_bf16(a[0][c], b1, acc[0][1], 0, 0, 0);
                acc[1][1] = __builtin_amdgcn_mfma_f32_16x16x32_bf16(a[1][c], b1, acc[1][1], 0, 0, 0);
            }
#pragma unroll
            for (int m = 0; m < 2; m++) {
#pragma unroll
                for (int r = 0; r < 4; r++)
                    se[m][r] += __builtin_amdgcn_exp2f(acc[m][0][r] + bs0)
                              + __builtin_amdgcn_exp2f(acc[m][1][r] + bs1);
            }
        }
        __syncthreads();
        cur ^= 1;
    }

#pragma unroll
    for (int m = 0; m < 2; m++) {
        f32x4 v = se[m];
#pragma unroll
        for (int d = 1; d < 16; d <<= 1) {
            v[0] += __shfl_xor(v[0], d);
            v[1] += __shfl_xor(v[1], d);
            v[2] += __shfl_xor(v[2], d);
            v[3] += __shfl_xor(v[3], d);
        }
        if (l15 == 0) {
            float* p = parts + (size_t)(vc * 2 + cg) * 6016 + row0 + m * 16 + q * 4;
            p[0] = v[0]; p[1] = v[1]; p[2] = v[2]; p[3] = v[3];
        }
    }
}

// ---------------- per-row loss ----------------
__global__ void k_final1(const float* __restrict__ parts, const float* __restrict__ tl,
                         float* __restrict__ rowloss) {
    int r = blockIdx.x * 128 + threadIdx.x;
    float tot = 0.f;
#pragma unroll 4
    for (int c = 0; c < 20; c++) tot += parts[(size_t)c * 6016 + r];
    rowloss[r] = logf(tot) - tl[r];
}

// ---------------- final mean ----------------
__global__ void k_final2(const float* __restrict__ rowloss, float* __restrict__ out) {
    __shared__ float red[512];
    int tid = threadIdx.x;
    float acc = 0.f;
    for (int r = tid; r < 6016; r += 512) acc += rowloss[r];
    red[tid] = acc;
    __syncthreads();
    for (int s = 256; s > 0; s >>= 1) {
        if (tid < s) red[tid] += red[tid + s];
        __syncthreads();
    }
    if (tid == 0) out[0] = red[0] / 6016.f;
}

extern "C" void kernel_launch(void* const* d_in, const int* in_sizes, int n_in,
                              void* d_out, int out_size, void* d_ws, size_t ws_size,
                              hipStream_t stream) {
    const int* doc = (const int*)d_in[0];
    const float* enc_emb = (const float*)d_in[1];
    const float* enc_Wih = (const float*)d_in[2];
    const float* enc_Whh = (const float*)d_in[3];
    const float* enc_bih = (const float*)d_in[4];
    const float* enc_bhh = (const float*)d_in[5];
    const float* doc_Wih = (const float*)d_in[6];
    const float* doc_Whh = (const float*)d_in[7];
    const float* doc_bih = (const float*)d_in[8];
    const float* doc_bhh = (const float*)d_in[9];
    const float* dec_emb = (const float*)d_in[10];
    const float* dec_Wih = (const float*)d_in[11];
    const float* dec_Whh = (const float*)d_in[12];
    const float* dec_bih = (const float*)d_in[13];
    const float* dec_bhh = (const float*)d_in[14];
    const float* fc_W = (const float*)d_in[15];
    const float* fc_b = (const float*)d_in[16];

    char* ws = (char*)d_ws;
    ushort_t* fcWb   = (ushort_t*)(ws + 0);          // 8,192,000 B
    float* sent      = (float*)(ws + 8192000);       // 65,536 B
    float* dvec      = (float*)(ws + 8257536);       // 512 B
    float* gidoc     = (float*)(ws + 8258048);       // 196,608 B
    float* gidec     = (float*)(ws + 8456192);       // 9,240,576 B
    ushort_t* h2b    = (ushort_t*)(ws + 17696768);   // 1,540,096 B
    float* tl        = (float*)(ws + 19236864);      // 24,064 B
    float* parts     = (float*)(ws + 19260928);      // 20*6016*4 = 481,280 B
    float* rowloss   = (float*)(ws + 19742208);      // 24,064 B
    ushort_t* wdoc   = (ushort_t*)(ws + 19766272);   // 98,304 B
    float* fcbs      = (float*)(ws + 19864576);      // 128,000 B
    ushort_t* wencih = (ushort_t*)(ws + 19992576);   // 49,152 B
    ushort_t* wenchh = (ushort_t*)(ws + 20041728);   // 98,304 B
    ushort_t* wdechh = (ushort_t*)(ws + 20140032);   // 98,304 B
    float* out = (float*)d_out;

    k_prep<<<168, 256, 0, stream>>>(enc_Wih, enc_Whh, dec_Whh, doc_Whh,
                                    wencih, wenchh, wdechh, wdoc);
    k_encoder<<<128, 768, 0, stream>>>(doc, enc_emb, wencih, wenchh, enc_bih, enc_bhh, sent);
    k_doc_gi<<<128, 384, 0, stream>>>(sent, doc_Wih, doc_bih, gidoc);
    k_mid<<<1 + 128 + 2016, 512, 0, stream>>>(gidoc, wdoc, doc_bhh, dvec,
                                              doc, dec_emb, dec_Wih, gidec,
                                              fc_W, fcWb, fc_b, fcbs);
    k_dec_seq<<<128, 768, 0, stream>>>(gidec, wdechh, dec_bhh, sent,
                                       dec_Wih, dec_bih, dvec, h2b);
    k_tl<<<1504, 256, 0, stream>>>(doc, h2b, fcWb, fc_b, tl);
    k_lse<<<47 * LSE_VC, 512, 0, stream>>>(h2b, fcWb, fcbs, parts);
    k_final1<<<47, 128, 0, stream>>>(parts, tl, rowloss);
    k_final2<<<1, 512, 0, stream>>>(rowloss, out);
}